// Round 1
// baseline (416.706 us; speedup 1.0000x reference)
//
#include <hip/hip_runtime.h>

#define N_NODES 100000
#define DIM 64
#define N_EDGES_EXPECT 1600000

// ---------------------------------------------------------------------------
// Kernel 1: scatter-add  aggr[row] += x[col]  over edges.
// One 64-lane wave per edge; lane = feature dim.
//   - x[col*64 + lane] is a fully coalesced 256B read per edge (L2/L3-resident:
//     x is only 25.6 MB).
//   - one f32 atomicAdd per lane into aggr (== d_out, pre-zeroed).
// ---------------------------------------------------------------------------
__global__ __launch_bounds__(256) void scatter_add_kernel(
    const float* __restrict__ x,
    const int* __restrict__ edge_index,  // [2, nEdges] : row ptr then col ptr
    float* __restrict__ aggr,
    int nEdges) {
  const int lane = threadIdx.x & 63;
  const int eBase = blockIdx.x * (blockDim.x >> 6) + (threadIdx.x >> 6);
  if (eBase >= nEdges) return;
  const int row = edge_index[eBase];            // dest
  const int col = edge_index[nEdges + eBase];   // src
  const float v = x[(size_t)col * DIM + lane];
  atomicAdd(&aggr[(size_t)row * DIM + lane], v);
}

// ---------------------------------------------------------------------------
// Kernel 2: in-place  out[r] = relu(aggr[r] @ W^T + b), W is [64,64] (row-major:
// W[j][k] multiplies input dim k producing output dim j).
// Block = 256 threads = 4 waves; each wave owns one row -> safe in-place
// (wave stages its row into LDS, then overwrites it; no cross-wave dependency).
// W staged in LDS padded to stride 65: sW[j][k] across lanes j at fixed k is
// stride-65 words -> free 2-way bank aliasing instead of 32-way conflict.
// sRow[wid][k] is wave-uniform -> broadcast, conflict-free.
// ---------------------------------------------------------------------------
__global__ __launch_bounds__(256) void linear_relu_inplace_kernel(
    float* __restrict__ io,
    const float* __restrict__ W,
    const float* __restrict__ b,
    int nRows) {
  __shared__ float sW[64][65];
  __shared__ float sRow[4][64];

  const int tid = threadIdx.x;
  // Stage W: 4096 floats / 256 threads = 16 per thread, coalesced.
  for (int i = tid; i < 64 * 64; i += 256) {
    sW[i >> 6][i & 63] = W[i];
  }
  __syncthreads();

  const int wid = tid >> 6;   // wave id in block: which row
  const int j   = tid & 63;   // output dim
  const int row = blockIdx.x * 4 + wid;
  if (row < nRows) {
    const size_t base = (size_t)row * DIM;
    sRow[wid][j] = io[base + j];
    // Intra-wave LDS dependency only; compiler inserts lgkmcnt waits.
    float acc = b[j];
#pragma unroll
    for (int k = 0; k < 64; ++k) {
      acc = fmaf(sRow[wid][k], sW[j][k], acc);
    }
    io[base + j] = fmaxf(acc, 0.0f);
  }
}

extern "C" void kernel_launch(void* const* d_in, const int* in_sizes, int n_in,
                              void* d_out, int out_size, void* d_ws, size_t ws_size,
                              hipStream_t stream) {
  const float* x  = (const float*)d_in[0];
  const int* ei   = (const int*)d_in[1];
  const float* W  = (const float*)d_in[2];
  const float* b  = (const float*)d_in[3];
  float* out      = (float*)d_out;

  const int nNodes = in_sizes[0] / DIM;         // 100000
  const int nEdges = in_sizes[1] / 2;           // 1600000

  // Zero the accumulator (d_out doubles as aggr buffer).
  hipMemsetAsync(d_out, 0, (size_t)out_size * sizeof(float), stream);

  // Scatter: 4 edges per 256-thread block.
  {
    const int edgesPerBlock = 4;
    const int grid = (nEdges + edgesPerBlock - 1) / edgesPerBlock;
    scatter_add_kernel<<<grid, 256, 0, stream>>>(x, ei, out, nEdges);
  }

  // In-place linear + bias + relu: 4 rows per block.
  {
    const int grid = (nNodes + 3) / 4;
    linear_relu_inplace_kernel<<<grid, 256, 0, stream>>>(out, W, b, nNodes);
  }
}

// Round 2
// 328.230 us; speedup vs baseline: 1.2696x; 1.2696x over previous
//
#include <hip/hip_runtime.h>

#define DIM 64
#define SCAN_BLK 256

// Workspace layout (bytes). Needs ~8.4 MB of d_ws.
#define WS_COUNT   0u              // int[nNodes]      (400,000 B)
#define WS_OFFSET  (512u*1024u)    // int[nNodes]
#define WS_CURSOR  (1024u*1024u)   // int[nNodes]
#define WS_BSUMS   (1536u*1024u)   // int[nScanBlocks] (<512)
#define WS_CSR     (2u*1024u*1024u)// int[nEdges]      (6,400,000 B)

// ---------------------------------------------------------------------------
// 1) Histogram of destination rows: count[row]++ (int atomics, 400 KB array).
// ---------------------------------------------------------------------------
__global__ __launch_bounds__(256) void hist_kernel(
    const int* __restrict__ ei, int* __restrict__ count, int nEdges) {
  int i = blockIdx.x * blockDim.x + threadIdx.x;
  if (i < nEdges) atomicAdd(&count[ei[i]], 1);
}

// ---------------------------------------------------------------------------
// 2a) Per-block reduction of counts -> blockSums.
// ---------------------------------------------------------------------------
__global__ __launch_bounds__(SCAN_BLK) void block_reduce_kernel(
    const int* __restrict__ count, int* __restrict__ blockSums, int n) {
  __shared__ int s[SCAN_BLK];
  int i = blockIdx.x * SCAN_BLK + threadIdx.x;
  s[threadIdx.x] = (i < n) ? count[i] : 0;
  __syncthreads();
  for (int off = SCAN_BLK / 2; off > 0; off >>= 1) {
    if (threadIdx.x < off) s[threadIdx.x] += s[threadIdx.x + off];
    __syncthreads();
  }
  if (threadIdx.x == 0) blockSums[blockIdx.x] = s[0];
}

// ---------------------------------------------------------------------------
// 2b) Exclusive scan of blockSums (single block, nBlocks <= 512).
// ---------------------------------------------------------------------------
__global__ __launch_bounds__(512) void scan_blocksums_kernel(
    int* __restrict__ blockSums, int nBlocks) {
  __shared__ int s[512];
  int t = threadIdx.x;
  int v = (t < nBlocks) ? blockSums[t] : 0;
  s[t] = v;
  __syncthreads();
  for (int off = 1; off < 512; off <<= 1) {
    int add = (t >= off) ? s[t - off] : 0;
    __syncthreads();
    s[t] += add;
    __syncthreads();
  }
  if (t < nBlocks) blockSums[t] = s[t] - v;  // exclusive
}

// ---------------------------------------------------------------------------
// 2c) Per-block exclusive scan + block offset -> offset[], and cursor=offset.
// ---------------------------------------------------------------------------
__global__ __launch_bounds__(SCAN_BLK) void block_scan_kernel(
    const int* __restrict__ count, const int* __restrict__ blockSums,
    int* __restrict__ offset, int* __restrict__ cursor, int n) {
  __shared__ int s[SCAN_BLK];
  int t = threadIdx.x;
  int i = blockIdx.x * SCAN_BLK + t;
  int v = (i < n) ? count[i] : 0;
  s[t] = v;
  __syncthreads();
  for (int off = 1; off < SCAN_BLK; off <<= 1) {
    int add = (t >= off) ? s[t - off] : 0;
    __syncthreads();
    s[t] += add;
    __syncthreads();
  }
  if (i < n) {
    int excl = s[t] - v + blockSums[blockIdx.x];
    offset[i] = excl;
    cursor[i] = excl;
  }
}

// ---------------------------------------------------------------------------
// 3) Fill CSR columns: pos = cursor[row]++ ; csr_col[pos] = col.
//    1.6M int atomics on 400 KB cursor array (low contention, L2-side).
// ---------------------------------------------------------------------------
__global__ __launch_bounds__(256) void fill_kernel(
    const int* __restrict__ ei, int* __restrict__ cursor,
    int* __restrict__ csr_col, int nEdges) {
  int i = blockIdx.x * blockDim.x + threadIdx.x;
  if (i >= nEdges) return;
  int row = ei[i];
  int col = ei[nEdges + i];
  int pos = atomicAdd(&cursor[row], 1);
  csr_col[pos] = col;
}

// ---------------------------------------------------------------------------
// 4) Fused gather + linear + bias + relu.
//    One 64-lane wave per node (lane = feature dim). Sums neighbor rows in
//    registers (coalesced 256B x-reads, x is L2/L3-resident), then 64x64
//    matvec through LDS:
//      - sW padded to stride 65: at step k lanes j read sW[j][k] -> addresses
//        j*65+k -> bank (j+k)%32, 2-way alias = free.
//      - sRow[w][k] is wave-uniform -> broadcast.
//    No atomics, single clean write per row.
// ---------------------------------------------------------------------------
__global__ __launch_bounds__(256) void gather_linear_kernel(
    const float* __restrict__ x, const int* __restrict__ csr_col,
    const int* __restrict__ offset, const int* __restrict__ count,
    const float* __restrict__ W, const float* __restrict__ b,
    float* __restrict__ out, int nNodes) {
  __shared__ float sW[64][65];
  __shared__ float sRow[4][64];

  const int tid = threadIdx.x;
  for (int i = tid; i < 64 * 64; i += 256) sW[i >> 6][i & 63] = W[i];
  __syncthreads();

  const int w = tid >> 6;
  const int lane = tid & 63;
  const int node = blockIdx.x * 4 + w;
  if (node >= nNodes) return;

  const int start = offset[node];
  const int deg = count[node];

  float acc = 0.0f;
  int e = 0;
  // 4-wide chunks: 4 independent col loads then 4 x-row loads -> MLP.
  for (; e + 4 <= deg; e += 4) {
    int c0 = csr_col[start + e + 0];
    int c1 = csr_col[start + e + 1];
    int c2 = csr_col[start + e + 2];
    int c3 = csr_col[start + e + 3];
    float v0 = x[(size_t)c0 * DIM + lane];
    float v1 = x[(size_t)c1 * DIM + lane];
    float v2 = x[(size_t)c2 * DIM + lane];
    float v3 = x[(size_t)c3 * DIM + lane];
    acc += v0 + v1 + v2 + v3;
  }
  for (; e < deg; ++e) {
    int c = csr_col[start + e];
    acc += x[(size_t)c * DIM + lane];
  }

  sRow[w][lane] = acc;  // intra-wave dependency only; lgkmcnt inserted
  float o = b[lane];
#pragma unroll
  for (int k = 0; k < 64; ++k) {
    o = fmaf(sRow[w][k], sW[lane][k], o);
  }
  out[(size_t)node * DIM + lane] = fmaxf(o, 0.0f);
}

extern "C" void kernel_launch(void* const* d_in, const int* in_sizes, int n_in,
                              void* d_out, int out_size, void* d_ws, size_t ws_size,
                              hipStream_t stream) {
  const float* x = (const float*)d_in[0];
  const int* ei  = (const int*)d_in[1];
  const float* W = (const float*)d_in[2];
  const float* b = (const float*)d_in[3];
  float* out     = (float*)d_out;

  const int nNodes = in_sizes[0] / DIM;  // 100000
  const int nEdges = in_sizes[1] / 2;    // 1600000

  char* ws = (char*)d_ws;
  int* count     = (int*)(ws + WS_COUNT);
  int* offset    = (int*)(ws + WS_OFFSET);
  int* cursor    = (int*)(ws + WS_CURSOR);
  int* blockSums = (int*)(ws + WS_BSUMS);
  int* csr_col   = (int*)(ws + WS_CSR);

  const int nScanBlocks = (nNodes + SCAN_BLK - 1) / SCAN_BLK;  // 391

  // Zero the histogram.
  hipMemsetAsync(count, 0, (size_t)nNodes * sizeof(int), stream);

  // 1) histogram
  {
    const int grid = (nEdges + 255) / 256;
    hist_kernel<<<grid, 256, 0, stream>>>(ei, count, nEdges);
  }
  // 2) exclusive scan -> offset, cursor
  block_reduce_kernel<<<nScanBlocks, SCAN_BLK, 0, stream>>>(count, blockSums, nNodes);
  scan_blocksums_kernel<<<1, 512, 0, stream>>>(blockSums, nScanBlocks);
  block_scan_kernel<<<nScanBlocks, SCAN_BLK, 0, stream>>>(count, blockSums, offset, cursor, nNodes);
  // 3) fill CSR
  {
    const int grid = (nEdges + 255) / 256;
    fill_kernel<<<grid, 256, 0, stream>>>(ei, cursor, csr_col, nEdges);
  }
  // 4) fused gather + linear + relu
  {
    const int grid = (nNodes + 3) / 4;
    gather_linear_kernel<<<grid, 256, 0, stream>>>(x, csr_col, offset, count, W, b, out, nNodes);
  }
}

// Round 3
// 292.543 us; speedup vs baseline: 1.4244x; 1.1220x over previous
//
#include <hip/hip_runtime.h>
#include <hip/hip_bf16.h>

#define DIM 64
#define SCAN_BLK 256

typedef __attribute__((ext_vector_type(8))) short bf16x8;   // 8 bf16 = 4 VGPRs
typedef __attribute__((ext_vector_type(4))) float f32x4;

// ---------------------------------------------------------------------------
// 1) Histogram of destination rows. 4 edges/thread, int4 loads, no-return
//    atomics (fire-and-forget -> no vmcnt wait on the atomic).
// ---------------------------------------------------------------------------
__global__ __launch_bounds__(256) void hist_kernel(
    const int* __restrict__ ei, int* __restrict__ count, int nEdges) {
  int i = (blockIdx.x * 256 + threadIdx.x) * 4;
  if (i + 4 <= nEdges) {
    int4 r = *(const int4*)(ei + i);
    atomicAdd(&count[r.x], 1);
    atomicAdd(&count[r.y], 1);
    atomicAdd(&count[r.z], 1);
    atomicAdd(&count[r.w], 1);
  } else {
    for (; i < nEdges; ++i) atomicAdd(&count[ei[i]], 1);
  }
}

// ---------------------------------------------------------------------------
// 2a) Per-block reduction of counts -> blockSums.
// ---------------------------------------------------------------------------
__global__ __launch_bounds__(SCAN_BLK) void block_reduce_kernel(
    const int* __restrict__ count, int* __restrict__ blockSums, int n) {
  __shared__ int s[SCAN_BLK];
  int i = blockIdx.x * SCAN_BLK + threadIdx.x;
  s[threadIdx.x] = (i < n) ? count[i] : 0;
  __syncthreads();
  for (int off = SCAN_BLK / 2; off > 0; off >>= 1) {
    if (threadIdx.x < off) s[threadIdx.x] += s[threadIdx.x + off];
    __syncthreads();
  }
  if (threadIdx.x == 0) blockSums[blockIdx.x] = s[0];
}

// ---------------------------------------------------------------------------
// 2b) Exclusive scan of blockSums (single block, nBlocks <= 512).
// ---------------------------------------------------------------------------
__global__ __launch_bounds__(512) void scan_blocksums_kernel(
    int* __restrict__ blockSums, int nBlocks) {
  __shared__ int s[512];
  int t = threadIdx.x;
  int v = (t < nBlocks) ? blockSums[t] : 0;
  s[t] = v;
  __syncthreads();
  for (int off = 1; off < 512; off <<= 1) {
    int add = (t >= off) ? s[t - off] : 0;
    __syncthreads();
    s[t] += add;
    __syncthreads();
  }
  if (t < nBlocks) blockSums[t] = s[t] - v;  // exclusive
}

// ---------------------------------------------------------------------------
// 2c) Per-block exclusive scan + block offset -> offset[], cursor[].
// ---------------------------------------------------------------------------
__global__ __launch_bounds__(SCAN_BLK) void block_scan_kernel(
    const int* __restrict__ count, const int* __restrict__ blockSums,
    int* __restrict__ offset, int* __restrict__ cursor, int n) {
  __shared__ int s[SCAN_BLK];
  int t = threadIdx.x;
  int i = blockIdx.x * SCAN_BLK + t;
  int v = (i < n) ? count[i] : 0;
  s[t] = v;
  __syncthreads();
  for (int off = 1; off < SCAN_BLK; off <<= 1) {
    int add = (t >= off) ? s[t - off] : 0;
    __syncthreads();
    s[t] += add;
    __syncthreads();
  }
  if (i < n) {
    int excl = s[t] - v + blockSums[blockIdx.x];
    offset[i] = excl;
    cursor[i] = excl;
  }
}

// ---------------------------------------------------------------------------
// 3) Fill CSR. 4 edges/thread: int4 row+col loads, 4 independent atomic
//    round-trips in flight, then 4 nontemporal scattered stores.
// ---------------------------------------------------------------------------
__global__ __launch_bounds__(256) void fill_kernel(
    const int* __restrict__ ei, int* __restrict__ cursor,
    int* __restrict__ csr_col, int nEdges) {
  int i = (blockIdx.x * 256 + threadIdx.x) * 4;
  if (i + 4 <= nEdges) {
    int4 r = *(const int4*)(ei + i);
    int4 c = *(const int4*)(ei + nEdges + i);
    int p0 = atomicAdd(&cursor[r.x], 1);
    int p1 = atomicAdd(&cursor[r.y], 1);
    int p2 = atomicAdd(&cursor[r.z], 1);
    int p3 = atomicAdd(&cursor[r.w], 1);
    __builtin_nontemporal_store(c.x, csr_col + p0);
    __builtin_nontemporal_store(c.y, csr_col + p1);
    __builtin_nontemporal_store(c.z, csr_col + p2);
    __builtin_nontemporal_store(c.w, csr_col + p3);
  } else {
    for (; i < nEdges; ++i) {
      int row = ei[i];
      int col = ei[nEdges + i];
      int pos = atomicAdd(&cursor[row], 1);
      csr_col[pos] = col;
    }
  }
}

// ---------------------------------------------------------------------------
// 4) Gather only: one wave per node (lane = feature dim), 8 edges in flight,
//    32-bit index math (saddr + voffset form), no LDS. Writes bf16 aggr.
// ---------------------------------------------------------------------------
__global__ __launch_bounds__(256) void gather_kernel(
    const float* __restrict__ x, const int* __restrict__ csr_col,
    const int* __restrict__ offset, const int* __restrict__ count,
    __hip_bfloat16* __restrict__ aggr, int nNodes) {
  const int w = threadIdx.x >> 6;
  const int lane = threadIdx.x & 63;
  const int node = blockIdx.x * 4 + w;
  if (node >= nNodes) return;
  const int start = offset[node];
  const int deg = count[node];
  const float* xl = x + lane;

  float a0 = 0.f, a1 = 0.f, a2 = 0.f, a3 = 0.f;
  float a4 = 0.f, a5 = 0.f, a6 = 0.f, a7 = 0.f;
  int e = 0;
  for (; e + 8 <= deg; e += 8) {
    const int* cp = csr_col + start + e;
    int c0 = cp[0], c1 = cp[1], c2 = cp[2], c3 = cp[3];
    int c4 = cp[4], c5 = cp[5], c6 = cp[6], c7 = cp[7];
    a0 += xl[c0 << 6]; a1 += xl[c1 << 6]; a2 += xl[c2 << 6]; a3 += xl[c3 << 6];
    a4 += xl[c4 << 6]; a5 += xl[c5 << 6]; a6 += xl[c6 << 6]; a7 += xl[c7 << 6];
  }
  float acc = ((a0 + a1) + (a2 + a3)) + ((a4 + a5) + (a6 + a7));
  for (; e < deg; ++e) acc += xl[csr_col[start + e] << 6];

  aggr[(size_t)node * DIM + lane] = __float2bfloat16(acc);
}

// ---------------------------------------------------------------------------
// 5a) W (f32 row-major [64][64], W[j][k]) -> bf16, same layout.
// ---------------------------------------------------------------------------
__global__ __launch_bounds__(256) void wprep_kernel(
    const float* __restrict__ W, __hip_bfloat16* __restrict__ Wbf) {
  int i = blockIdx.x * 256 + threadIdx.x;
  if (i < DIM * DIM) Wbf[i] = __float2bfloat16(W[i]);
}

// ---------------------------------------------------------------------------
// 5b) GEMM: out[n][j] = relu(sum_k aggr[n][k] * W[j][k] + bias[j]) via
//     mfma_f32_16x16x32_bf16. Block = 4 waves x 16 nodes = 64 nodes.
//     A frag: lane l holds A[l&15][(l>>4)*8 + e]  (16B contiguous load)
//     B frag: lane l holds B[(l>>4)*8+e][l&15] = W[l&15 + 16*jt][k] (16B load)
//     C/D:    col = lane&15 (=j sub), row = (lane>>4)*4 + reg (=node sub)
// ---------------------------------------------------------------------------
__global__ __launch_bounds__(256) void gemm_kernel(
    const __hip_bfloat16* __restrict__ aggr, const __hip_bfloat16* __restrict__ Wbf,
    const float* __restrict__ bias, float* __restrict__ out, int nNodes) {
  const int w = threadIdx.x >> 6;
  const int lane = threadIdx.x & 63;
  const int nodeBase = blockIdx.x * 64 + w * 16;
  const int r = lane & 15;
  const int kg = lane >> 4;

  int nodeA = nodeBase + r;
  if (nodeA >= nNodes) nodeA = nNodes - 1;  // clamp (reads only)
  const ushort* aRow = (const ushort*)aggr + (size_t)nodeA * DIM + kg * 8;
  bf16x8 a0 = *(const bf16x8*)(aRow);        // k in [kg*8, kg*8+8)
  bf16x8 a1 = *(const bf16x8*)(aRow + 32);   // k + 32

  f32x4 acc[4] = {f32x4{0,0,0,0}, f32x4{0,0,0,0}, f32x4{0,0,0,0}, f32x4{0,0,0,0}};
#pragma unroll
  for (int jt = 0; jt < 4; ++jt) {
    const ushort* bRow = (const ushort*)Wbf + (jt * 16 + r) * DIM + kg * 8;
    bf16x8 b0 = *(const bf16x8*)(bRow);
    bf16x8 b1 = *(const bf16x8*)(bRow + 32);
    acc[jt] = __builtin_amdgcn_mfma_f32_16x16x32_bf16(a0, b0, acc[jt], 0, 0, 0);
    acc[jt] = __builtin_amdgcn_mfma_f32_16x16x32_bf16(a1, b1, acc[jt], 0, 0, 0);
  }

#pragma unroll
  for (int jt = 0; jt < 4; ++jt) {
    int j = jt * 16 + r;
    float bj = bias[j];
#pragma unroll
    for (int q = 0; q < 4; ++q) {
      int node = nodeBase + kg * 4 + q;
      if (node < nNodes) out[(size_t)node * DIM + j] = fmaxf(acc[jt][q] + bj, 0.f);
    }
  }
}

// ---------------------------------------------------------------------------
// Fallback fused gather+linear (round-2 path) if ws is too small for aggr.
// ---------------------------------------------------------------------------
__global__ __launch_bounds__(256) void gather_linear_kernel(
    const float* __restrict__ x, const int* __restrict__ csr_col,
    const int* __restrict__ offset, const int* __restrict__ count,
    const float* __restrict__ W, const float* __restrict__ bias,
    float* __restrict__ out, int nNodes) {
  __shared__ float sW[64][65];
  __shared__ float sRow[4][64];
  const int tid = threadIdx.x;
  for (int i = tid; i < 64 * 64; i += 256) sW[i >> 6][i & 63] = W[i];
  __syncthreads();
  const int w = tid >> 6;
  const int lane = tid & 63;
  const int node = blockIdx.x * 4 + w;
  if (node >= nNodes) return;
  const int start = offset[node];
  const int deg = count[node];
  float acc = 0.0f;
  int e = 0;
  for (; e + 4 <= deg; e += 4) {
    int c0 = csr_col[start + e + 0];
    int c1 = csr_col[start + e + 1];
    int c2 = csr_col[start + e + 2];
    int c3 = csr_col[start + e + 3];
    acc += x[(size_t)c0 * DIM + lane] + x[(size_t)c1 * DIM + lane] +
           x[(size_t)c2 * DIM + lane] + x[(size_t)c3 * DIM + lane];
  }
  for (; e < deg; ++e) acc += x[(size_t)csr_col[start + e] * DIM + lane];
  sRow[w][lane] = acc;
  float o = bias[lane];
#pragma unroll
  for (int k = 0; k < 64; ++k) o = fmaf(sRow[w][k], sW[lane][k], o);
  out[(size_t)node * DIM + lane] = fmaxf(o, 0.0f);
}

extern "C" void kernel_launch(void* const* d_in, const int* in_sizes, int n_in,
                              void* d_out, int out_size, void* d_ws, size_t ws_size,
                              hipStream_t stream) {
  const float* x = (const float*)d_in[0];
  const int* ei  = (const int*)d_in[1];
  const float* W = (const float*)d_in[2];
  const float* b = (const float*)d_in[3];
  float* out     = (float*)d_out;

  const int nNodes = in_sizes[0] / DIM;  // 100000
  const int nEdges = in_sizes[1] / 2;    // 1600000

  // ws layout (256B-aligned slabs)
  size_t off = 0;
  auto take = [&](size_t bytes) {
    size_t r = off;
    off += (bytes + 255) & ~(size_t)255;
    return r;
  };
  char* ws = (char*)d_ws;
  int* count     = (int*)(ws + take((size_t)nNodes * 4));
  int* offset    = (int*)(ws + take((size_t)nNodes * 4));
  int* cursor    = (int*)(ws + take((size_t)nNodes * 4));
  int* blockSums = (int*)(ws + take(2048 * 4));
  __hip_bfloat16* Wbf = (__hip_bfloat16*)(ws + take(DIM * DIM * 2));
  int* csr_col   = (int*)(ws + take((size_t)nEdges * 4));
  size_t aggrOff = take((size_t)nNodes * DIM * 2);
  __hip_bfloat16* aggr = (__hip_bfloat16*)(ws + aggrOff);
  const bool fullPath = (ws_size >= off);

  const int nScanBlocks = (nNodes + SCAN_BLK - 1) / SCAN_BLK;  // 391

  hipMemsetAsync(count, 0, (size_t)nNodes * sizeof(int), stream);

  // 1) histogram (4 edges per thread)
  {
    const int nThreads = (nEdges + 3) / 4;
    hist_kernel<<<(nThreads + 255) / 256, 256, 0, stream>>>(ei, count, nEdges);
  }
  // 2) exclusive scan
  block_reduce_kernel<<<nScanBlocks, SCAN_BLK, 0, stream>>>(count, blockSums, nNodes);
  scan_blocksums_kernel<<<1, 512, 0, stream>>>(blockSums, nScanBlocks);
  block_scan_kernel<<<nScanBlocks, SCAN_BLK, 0, stream>>>(count, blockSums, offset, cursor, nNodes);
  // 3) fill CSR (4 edges per thread)
  {
    const int nThreads = (nEdges + 3) / 4;
    fill_kernel<<<(nThreads + 255) / 256, 256, 0, stream>>>(ei, cursor, csr_col, nEdges);
  }

  if (fullPath) {
    // 4) gather -> bf16 aggr
    gather_kernel<<<(nNodes + 3) / 4, 256, 0, stream>>>(x, csr_col, offset, count, aggr, nNodes);
    // 5) W -> bf16, then MFMA GEMM + bias + relu
    wprep_kernel<<<(DIM * DIM + 255) / 256, 256, 0, stream>>>(W, Wbf);
    gemm_kernel<<<(nNodes + 63) / 64, 256, 0, stream>>>(aggr, Wbf, b, out, nNodes);
  } else {
    // fallback: fused f32 path (round-2)
    gather_linear_kernel<<<(nNodes + 3) / 4, 256, 0, stream>>>(x, csr_col, offset, count, W, b, out, nNodes);
  }
}